// Round 2
// baseline (935.070 us; speedup 1.0000x reference)
//
#include <hip/hip_runtime.h>
#include <hip/hip_bf16.h>

typedef _Float16 half8 __attribute__((ext_vector_type(8)));
typedef float f32x4 __attribute__((ext_vector_type(4)));

__device__ __forceinline__ unsigned short f2h(float f) {
  _Float16 h = (_Float16)f;
  return __builtin_bit_cast(unsigned short, h);
}
__device__ __forceinline__ float h2f(unsigned short u) {
  return (float)__builtin_bit_cast(_Float16, u);
}

// async global->LDS, 16B per lane. LDS base must be wave-uniform.
__device__ __forceinline__ void gload16(const unsigned short* g, unsigned short* l) {
  __builtin_amdgcn_global_load_lds(
      (const __attribute__((address_space(1))) unsigned int*)g,
      (__attribute__((address_space(3))) unsigned int*)l, 16, 0, 0);
}

// ---------------- f32 -> f16 convert ----------------
__global__ __launch_bounds__(256) void cvt_f32_f16_kernel(
    const float* __restrict__ in, unsigned short* __restrict__ out, int n4) {
  int i = blockIdx.x * 256 + threadIdx.x;
  if (i < n4) {
    float4 v = ((const float4*)in)[i];
    ushort4 o;
    o.x = f2h(v.x); o.y = f2h(v.y); o.z = f2h(v.z); o.w = f2h(v.w);
    ((ushort4*)out)[i] = o;
  }
}

// ---------------- NT GEMM: C[m,n] = sum_k A[m,k] * B[n,k] ----------------
// A: (M,K) fp16 row-major, B: (N,K) fp16 row-major. 128x128 tile, BK=64,
// 2x2 waves, global_load_lds w/ XOR swizzle (linear dest + pre-swizzled src).
// EPI: 0 plain fp16, 1 rope (oscale pre-scale), 2 swish fp16, 3 f32 store.
template <int EPI>
__global__ __launch_bounds__(256) void gemm_nt(
    const unsigned short* __restrict__ A, const unsigned short* __restrict__ Bm,
    unsigned short* __restrict__ Ch, float* __restrict__ Cf,
    int M, int N, int K,
    const float* __restrict__ sintab, const float* __restrict__ costab,
    float oscale) {
  __shared__ __align__(16) unsigned short As[128 * 64];
  __shared__ __align__(16) unsigned short Bs[128 * 64];
  const int tid = threadIdx.x;
  const int lane = tid & 63, w = tid >> 6;
  const int wm = w >> 1, wn = w & 1;
  const int m0 = blockIdx.y * 128, n0 = blockIdx.x * 128;
  const int lrow = lane & 15, lk = lane >> 4;
  const int sw = (lane & 7) << 4;

  f32x4 acc[4][4] = {};
  const int KT = K >> 6;
  for (int kt = 0; kt < KT; ++kt) {
    __syncthreads();
#pragma unroll
    for (int q = 0; q < 4; ++q) {
      int base16 = q * 256 + w * 64;
      int idx16 = base16 + lane;
      int row = idx16 >> 3;                 // 128B rows
      int qb = (idx16 & 7) * 16;
      int qbs = qb ^ ((row & 7) << 4);
      gload16(A + ((size_t)(m0 + row) * K + kt * 64 + (qbs >> 1)), &As[base16 * 8]);
      gload16(Bm + ((size_t)(n0 + row) * K + kt * 64 + (qbs >> 1)), &Bs[base16 * 8]);
    }
    __syncthreads();
#pragma unroll
    for (int k2 = 0; k2 < 2; ++k2) {
      half8 af[4], bf[4];
      int kb = k2 * 64 + lk * 16;
#pragma unroll
      for (int i = 0; i < 4; ++i) {
        int ra = wm * 64 + i * 16 + lrow;
        af[i] = *(const half8*)((const char*)As + ra * 128 + (kb ^ sw));
        int rb = wn * 64 + i * 16 + lrow;
        bf[i] = *(const half8*)((const char*)Bs + rb * 128 + (kb ^ sw));
      }
#pragma unroll
      for (int i = 0; i < 4; ++i)
#pragma unroll
        for (int j = 0; j < 4; ++j)
          acc[i][j] = __builtin_amdgcn_mfma_f32_16x16x32_f16(af[i], bf[j], acc[i][j], 0, 0, 0);
    }
  }
  // epilogue: C/D layout col=lane&15, row=(lane>>4)*4+reg (m89-verified)
#pragma unroll
  for (int i = 0; i < 4; ++i) {
#pragma unroll
    for (int j = 0; j < 4; ++j) {
      int col = wn * 64 + j * 16 + lrow;
      int gn = n0 + col;
#pragma unroll
      for (int r = 0; r < 4; ++r) {
        int gm = m0 + wm * 64 + i * 16 + lk * 4 + r;
        float v = acc[i][j][r];
        if (EPI == 1) {
          float p = __shfl_xor(v, 1);  // partner at n^1 (same row: lane^1 keeps lane>>4)
          int t = gm & 2047, d = gn & 255;
          float c = costab[t * 256 + d], s = sintab[t * 256 + d];
          float rot = (lane & 1) ? p : -p;  // even d: -x[d+1]; odd d: x[d-1]
          Ch[(size_t)gm * N + gn] = f2h(oscale * (v * c + rot * s));
        } else if (EPI == 2) {
          Ch[(size_t)gm * N + gn] = f2h(v / (1.0f + expf(-v)));
        } else if (EPI == 3) {
          Cf[(size_t)gm * N + gn] = v;
        } else {
          Ch[(size_t)gm * N + gn] = f2h(v);
        }
      }
    }
  }
}

// ---------------- V transpose: vv[b*T + t][n] -> vT[b][n][t] ----------------
__global__ __launch_bounds__(256) void transpose_v_kernel(
    const unsigned short* __restrict__ vv, unsigned short* __restrict__ vT) {
  __shared__ __align__(16) unsigned short tile[64][72];
  int t0 = blockIdx.x * 64;
  int n0 = blockIdx.y * 64;
  int b = blockIdx.z;
  int tid = threadIdx.x;
#pragma unroll
  for (int q = 0; q < 2; ++q) {
    int idx = q * 256 + tid;
    int r = idx >> 3, c8 = (idx & 7) * 8;
    const unsigned short* src = vv + ((size_t)(b * 2048 + t0 + r)) * 4096 + n0 + c8;
    *(uint4*)&tile[r][c8] = *(const uint4*)src;
  }
  __syncthreads();
#pragma unroll
  for (int q = 0; q < 2; ++q) {
    int idx = q * 256 + tid;
    int rn = idx >> 3, c8 = (idx & 7) * 8;
    unsigned short tmp[8];
#pragma unroll
    for (int e = 0; e < 8; ++e) tmp[e] = tile[c8 + e][rn];
    unsigned short* dst = vT + ((size_t)b * 4096 + n0 + rn) * 2048 + t0 + c8;
    *(uint4*)dst = *(uint4*)tmp;
  }
}

// ---------------- fused retention + denom + groupnorm + gate ----------------
// grid: (T/64, NH, B), 256 threads (4 waves). Wave w owns output rows w*16..+16.
__global__ __launch_bounds__(256) void retention_kernel(
    const unsigned short* __restrict__ qr, const unsigned short* __restrict__ kr,
    const unsigned short* __restrict__ vT, const unsigned short* __restrict__ sg,
    const float* __restrict__ dm, unsigned short* __restrict__ gated) {
  __shared__ __align__(16) unsigned short Ks[64 * 256];  // [j][k] 512B rows, swz
  __shared__ __align__(16) unsigned short Vs[512 * 64];  // [d][j] 128B rows, swz
  __shared__ __align__(16) unsigned short Ss[64 * 64];   // [i][j] 128B rows, swz
  const int T = 2048, E = 2048, Vd = 4096;
  const int tid = threadIdx.x, lane = tid & 63, w = tid >> 6;
  const int lrow = lane & 15, lk = lane >> 4, sw = (lane & 7) << 4;
  const int ib = blockIdx.x, h = blockIdx.y, b = blockIdx.z;
  const int i0 = ib * 64;

  // hoist Q fragments (rows i0+w*16+lrow, K=256)
  half8 qf[8];
  {
    const unsigned short* qrow =
        qr + ((size_t)(b * T + i0 + w * 16 + lrow)) * E + h * 256 + lk * 8;
#pragma unroll
    for (int kt = 0; kt < 8; ++kt) qf[kt] = *(const half8*)(qrow + kt * 32);
  }
  f32x4 accv[32] = {};
  float rowAbs[4] = {0.f, 0.f, 0.f, 0.f};

  const unsigned short* krB = kr + ((size_t)(b * T)) * E + h * 256;
  const unsigned short* vtB = vT + ((size_t)b * Vd + h * 512) * T;

  const int ntiles = ib + 1;
  for (int jt = 0; jt < ntiles; ++jt) {
    int j0 = jt * 64;
    __syncthreads();
    // stage K tile (64 x 256 fp16, 512B rows)
#pragma unroll
    for (int q = 0; q < 8; ++q) {
      int base16 = q * 256 + w * 64;
      int idx16 = base16 + lane;
      int row = idx16 >> 5;
      int qb = (idx16 & 31) * 16;
      int qbs = qb ^ ((row & 7) << 4);
      gload16(krB + (size_t)(j0 + row) * E + (qbs >> 1), &Ks[base16 * 8]);
    }
    // stage V^T tile (512 x 64 fp16, 128B rows)
#pragma unroll
    for (int q = 0; q < 16; ++q) {
      int base16 = q * 256 + w * 64;
      int idx16 = base16 + lane;
      int row = idx16 >> 3;
      int qb = (idx16 & 7) * 16;
      int qbs = qb ^ ((row & 7) << 4);
      gload16(vtB + (size_t)row * T + j0 + (qbs >> 1), &Vs[base16 * 8]);
    }
    __syncthreads();

    // S = Qr @ Kr^T  (wave rows w*16..+16, cols j0..j0+64)
    f32x4 sacc[4] = {};
#pragma unroll
    for (int kt = 0; kt < 8; ++kt) {
      int kb = kt * 64 + lk * 16;
#pragma unroll
      for (int c = 0; c < 4; ++c) {
        int row = c * 16 + lrow;
        half8 kf = *(const half8*)((const char*)Ks + row * 512 + (kb ^ sw));
        sacc[c] = __builtin_amdgcn_mfma_f32_16x16x32_f16(qf[kt], kf, sacc[c], 0, 0, 0);
      }
    }
    // decay multiply (dm==0 above diagonal => causal), |S| row-partials, S->LDS
#pragma unroll
    for (int c = 0; c < 4; ++c) {
#pragma unroll
      for (int r = 0; r < 4; ++r) {
        int rl = lk * 4 + r;
        int gi = i0 + w * 16 + rl;
        int gj = j0 + c * 16 + lrow;
        float dmv = dm[((size_t)h * T + gi) * T + gj];
        float sv = sacc[c][r] * dmv;
        rowAbs[r] += fabsf(sv);
        int srow = w * 16 + rl;
        int scb = (c * 16 + lrow) * 2;
        *(unsigned short*)((char*)Ss + srow * 128 + (scb ^ ((srow & 7) << 4))) = f2h(sv);
      }
    }
    __syncthreads();
    // out += S @ V  == S(i,j) x vT(d,j): NT-form MFMA
    half8 sfr[2];
#pragma unroll
    for (int k2 = 0; k2 < 2; ++k2) {
      int rowS = w * 16 + lrow;
      sfr[k2] = *(const half8*)((const char*)Ss + rowS * 128 + ((k2 * 64 + lk * 16) ^ sw));
    }
#pragma unroll
    for (int nc = 0; nc < 32; ++nc) {
#pragma unroll
      for (int k2 = 0; k2 < 2; ++k2) {
        int rowV = nc * 16 + lrow;
        half8 vf = *(const half8*)((const char*)Vs + rowV * 128 + ((k2 * 64 + lk * 16) ^ sw));
        accv[nc] = __builtin_amdgcn_mfma_f32_16x16x32_f16(sfr[k2], vf, accv[nc], 0, 0, 0);
      }
    }
  }

  // denom = clip(sum |S|, 1, 5e4): reduce across the 16 lanes sharing each row
#pragma unroll
  for (int r = 0; r < 4; ++r) {
    float v = rowAbs[r];
    v += __shfl_xor(v, 1); v += __shfl_xor(v, 2);
    v += __shfl_xor(v, 4); v += __shfl_xor(v, 8);
    rowAbs[r] = fminf(fmaxf(v, 1.0f), 50000.0f);
  }
  float ssum[4] = {0.f, 0.f, 0.f, 0.f};
#pragma unroll
  for (int nc = 0; nc < 32; ++nc)
#pragma unroll
    for (int r = 0; r < 4; ++r) {
      float v = accv[nc][r] / rowAbs[r];
      accv[nc][r] = v;
      ssum[r] += v * v;
    }
#pragma unroll
  for (int r = 0; r < 4; ++r) {
    float v = ssum[r];
    v += __shfl_xor(v, 1); v += __shfl_xor(v, 2);
    v += __shfl_xor(v, 4); v += __shfl_xor(v, 8);
    ssum[r] = rsqrtf(v * (1.0f / 512.0f) + 1e-6f);
  }
  // gated = swish(g) * groupnorm(out); sg already holds swish(g)
#pragma unroll
  for (int r = 0; r < 4; ++r) {
    int gi = i0 + w * 16 + lk * 4 + r;
    size_t rowoff = ((size_t)(b * T + gi)) * Vd + h * 512;
#pragma unroll
    for (int nc = 0; nc < 32; ++nc) {
      int col = nc * 16 + lrow;
      float gv = h2f(sg[rowoff + col]);
      gated[rowoff + col] = f2h(accv[nc][r] * ssum[r] * gv);
    }
  }
}

extern "C" void kernel_launch(void* const* d_in, const int* in_sizes, int n_in,
                              void* d_out, int out_size, void* d_ws, size_t ws_size,
                              hipStream_t stream) {
  (void)in_sizes; (void)n_in; (void)out_size; (void)ws_size;
  const float* hidden = (const float*)d_in[0];
  const float* sintab = (const float*)d_in[1];
  const float* costab = (const float*)d_in[2];
  const float* dmask  = (const float*)d_in[3];
  const float* Wq = (const float*)d_in[4];
  const float* Wk = (const float*)d_in[5];
  const float* Wv = (const float*)d_in[6];
  const float* Wg = (const float*)d_in[7];
  const float* Wo = (const float*)d_in[8];
  float* outp = (float*)d_out;
  char* ws = (char*)d_ws;
  const size_t MiB = (size_t)1 << 20;
  unsigned short* xb   = (unsigned short*)(ws + 0 * MiB);    // 16 MiB  x fp16
  unsigned short* WqH  = (unsigned short*)(ws + 16 * MiB);   // 8 MiB
  unsigned short* WkH  = (unsigned short*)(ws + 24 * MiB);   // 8 MiB
  unsigned short* WvH  = (unsigned short*)(ws + 32 * MiB);   // 16 MiB
  unsigned short* WgH  = (unsigned short*)(ws + 48 * MiB);   // 16 MiB
  unsigned short* WoH  = (unsigned short*)(ws + 64 * MiB);   // 16 MiB
  unsigned short* qrb  = (unsigned short*)(ws + 80 * MiB);   // 16 MiB
  unsigned short* krb  = (unsigned short*)(ws + 96 * MiB);   // 16 MiB
  unsigned short* vvb  = (unsigned short*)(ws + 112 * MiB);  // 32 MiB
  unsigned short* vTb  = (unsigned short*)(ws + 144 * MiB);  // 32 MiB
  unsigned short* sgb  = (unsigned short*)(ws + 176 * MiB);  // 32 MiB  (end 208 MiB)
  unsigned short* gatedb = vvb;  // vv dead after transpose

  auto cvt = [&](const float* in, unsigned short* out, int n) {
    cvt_f32_f16_kernel<<<dim3((n / 4 + 255) / 256), 256, 0, stream>>>(in, out, n / 4);
  };
  cvt(hidden, xb, 4096 * 2048);
  cvt(Wq, WqH, 2048 * 2048);
  cvt(Wk, WkH, 2048 * 2048);
  cvt(Wv, WvH, 4096 * 2048);
  cvt(Wg, WgH, 4096 * 2048);
  cvt(Wo, WoH, 2048 * 4096);

  // Q, K projections + RoPE (k pre-scaled by kd^-0.5 = 1/16)
  gemm_nt<1><<<dim3(16, 32), 256, 0, stream>>>(xb, WqH, qrb, nullptr, 4096, 2048, 2048, sintab, costab, 1.0f);
  gemm_nt<1><<<dim3(16, 32), 256, 0, stream>>>(xb, WkH, krb, nullptr, 4096, 2048, 2048, sintab, costab, 0.0625f);
  // V projection, G projection (+swish fused)
  gemm_nt<0><<<dim3(32, 32), 256, 0, stream>>>(xb, WvH, vvb, nullptr, 4096, 4096, 2048, nullptr, nullptr, 0.f);
  gemm_nt<2><<<dim3(32, 32), 256, 0, stream>>>(xb, WgH, sgb, nullptr, 4096, 4096, 2048, nullptr, nullptr, 0.f);
  transpose_v_kernel<<<dim3(32, 64, 2), 256, 0, stream>>>(vvb, vTb);
  // fused retention + denom + groupnorm + gate
  retention_kernel<<<dim3(32, 8, 2), 256, 0, stream>>>(qrb, krb, vTb, sgb, dmask, gatedb);
  // output projection, f32 store
  gemm_nt<3><<<dim3(16, 32), 256, 0, stream>>>(gatedb, WoH, nullptr, outp, 4096, 2048, 4096, nullptr, nullptr, 0.f);
}